// Round 2
// baseline (1014.351 us; speedup 1.0000x reference)
//
#include <hip/hip_runtime.h>

#define NUM_HEADS 32
#define HEAD_DIM 128
#define NUM_KV_HEADS 8
#define SEQ 2048
#define BATCH 2
#define BQ 64            // q rows per block (16 per wave, 4 waves)
#define TKV 32           // kv rows per iteration
#define PSTR 40          // P round-trip LDS row stride (shorts)
#define QROW (NUM_HEADS * HEAD_DIM)      // 4096 floats
#define KROW (NUM_KV_HEADS * HEAD_DIM)   // 1024 floats

typedef __attribute__((ext_vector_type(8))) short bf16x8;
typedef __attribute__((ext_vector_type(4))) float f32x4;

__device__ __forceinline__ short f2bf(float f) {
    unsigned u = __float_as_uint(f);
    u += 0x7fffu + ((u >> 16) & 1u);
    return (short)(u >> 16);
}
__device__ __forceinline__ unsigned pack2(float a, float b) {
    return ((unsigned)(unsigned short)f2bf(a)) | (((unsigned)(unsigned short)f2bf(b)) << 16);
}
__device__ __forceinline__ float fexp2(float x) { return __builtin_amdgcn_exp2f(x); }

// ---- pre-pass: K fp32 [b][s][hk][d] -> bf16 [b][hk][s][d] ----
__global__ __launch_bounds__(256)
void conv_k(const float* __restrict__ kg, short* __restrict__ kb) {
    int gid = blockIdx.x * 256 + threadIdx.x;       // 524288 threads, 8 elems each
    int d   = (gid & 15) * 8;
    int idx = gid >> 4;                             // (b*8+hk)*2048 + s
    int s   = idx & (SEQ - 1);
    int hk  = (idx >> 11) & 7;
    int b   = idx >> 14;
    const float* in = kg + ((size_t)(b * SEQ + s) * NUM_KV_HEADS + hk) * HEAD_DIM + d;
    float4 a = *(const float4*)in;
    float4 c = *(const float4*)(in + 4);
    bf16x8 o = { f2bf(a.x), f2bf(a.y), f2bf(a.z), f2bf(a.w),
                 f2bf(c.x), f2bf(c.y), f2bf(c.z), f2bf(c.w) };
    *(bf16x8*)(kb + (size_t)gid * 8) = o;
}

// ---- pre-pass: V fp32 [b][s][hk][d] -> bf16 V^T [b][hk][d][s] ----
// lane owns column d, 8 consecutive s. Reads coalesced (row-wise); 16B stores scattered (L2 absorbs).
__global__ __launch_bounds__(256)
void conv_vt(const float* __restrict__ vg, short* __restrict__ vt) {
    int gid = blockIdx.x * 256 + threadIdx.x;       // 524288 threads
    int d   = gid & 127;
    int s0  = ((gid >> 7) & 255) * 8;
    int hk  = (gid >> 15) & 7;
    int b   = gid >> 18;
    const float* in = vg + ((size_t)(b * SEQ + s0) * NUM_KV_HEADS + hk) * HEAD_DIM + d;
    bf16x8 o;
#pragma unroll
    for (int i = 0; i < 8; ++i) o[i] = f2bf(in[(size_t)i * KROW]);
    *(bf16x8*)(vt + (((size_t)(b * NUM_KV_HEADS + hk) * HEAD_DIM + d) * SEQ + s0)) = o;
}

// ---- main: barrier-free flash attention, S^T formulation ----
// S^T = K·Q^T  -> C layout: row(m)=kv=quad*4+r, col(n)=q=l16  => softmax state per-lane (q=l16)
// O^T accumulate: mfma(A=V^T frag, B=P frag) -> row(m)=d, col(n)=q=l16 => alpha rescale shuffle-free
__global__ __launch_bounds__(256, 4)
void fattn_kernel(const float* __restrict__ qg, const short* __restrict__ kb,
                  const short* __restrict__ vt, float* __restrict__ outg) {
    const int tid  = threadIdx.x;
    const int wave = tid >> 6;
    const int lane = tid & 63;
    const int g    = lane >> 4;     // quad
    const int l16  = lane & 15;

    const int qt = (int)gridDim.x - 1 - (int)blockIdx.x;   // heavy tiles first
    const int h  = blockIdx.y;
    const int b  = blockIdx.z;
    const int hk = h >> 2;
    const int q0w  = qt * BQ + wave * 16;    // this wave's q base
    const int qrow = q0w + l16;              // this lane's q row (softmax + store)

    __shared__ short Pl[4][16 * PSTR];       // per-wave P round-trip, no cross-wave use

    // Q fragments (B-operand layout: n=q=l16, k=quad*8+j), fp32 loaded once
    bf16x8 qf[4];
    {
        const float* qp = qg + (size_t)(b * SEQ + qrow) * QROW + h * HEAD_DIM + g * 8;
#pragma unroll
        for (int s = 0; s < 4; ++s) {
            float4 a = *(const float4*)(qp + s * 32);
            float4 c = *(const float4*)(qp + s * 32 + 4);
            bf16x8 f = { f2bf(a.x), f2bf(a.y), f2bf(a.z), f2bf(a.w),
                         f2bf(c.x), f2bf(c.y), f2bf(c.z), f2bf(c.w) };
            qf[s] = f;
        }
    }

    // per-lane base pointers
    const short* kln = kb + (size_t)(b * NUM_KV_HEADS + hk) * SEQ * HEAD_DIM
                          + (size_t)l16 * HEAD_DIM + g * 8;       // + (kv0+nt*16)*HD + s*32
    const short* vln = vt + (size_t)(b * NUM_KV_HEADS + hk) * HEAD_DIM * SEQ
                          + (size_t)l16 * SEQ + g * 8;            // + dt*16*SEQ + kv0

    f32x4 o[8];
#pragma unroll
    for (int i = 0; i < 8; ++i) o[i] = (f32x4){0.f, 0.f, 0.f, 0.f};
    float rm = -1e30f, rl = 0.f;

    const float sscale = 0.08838834764831845f * 1.4426950408889634f;  // scale*log2(e)
    const int ntk = (q0w + 16 + TKV - 1) / TKV;   // per-WAVE causal trip count

    for (int kt = 0; kt < ntk; ++kt) {
        const int kv0 = kt * TKV;

        // K fragments (A-operand: m=kv=l16 within tile, k=d)
        bf16x8 kf[2][4];
#pragma unroll
        for (int nt = 0; nt < 2; ++nt)
#pragma unroll
            for (int s = 0; s < 4; ++s)
                kf[nt][s] = *(const bf16x8*)(kln + (size_t)(kv0 + nt * 16) * HEAD_DIM + s * 32);

        // S^T = K·Q^T
        f32x4 sacc[2];
#pragma unroll
        for (int nt = 0; nt < 2; ++nt) {
            f32x4 acc = {0.f, 0.f, 0.f, 0.f};
#pragma unroll
            for (int s = 0; s < 4; ++s)
                acc = __builtin_amdgcn_mfma_f32_16x16x32_bf16(kf[nt][s], qf[s], acc, 0, 0, 0);
            sacc[nt] = acc;
        }

        // V^T fragments issued early so the loads overlap the softmax chain
        bf16x8 vf[8];
#pragma unroll
        for (int dt = 0; dt < 8; ++dt)
            vf[dt] = *(const bf16x8*)(vln + (size_t)(dt * 16) * SEQ + kv0);

        // masked online softmax; the whole row q=l16 lives across the 4 quads
        float sc[2][4];
        float mx = -1e30f;
        const int kvb = kv0 + g * 4;
#pragma unroll
        for (int nt = 0; nt < 2; ++nt)
#pragma unroll
            for (int r = 0; r < 4; ++r) {
                float sv = sacc[nt][r] * sscale;
                sv = (kvb + nt * 16 + r <= qrow) ? sv : -1e30f;
                sc[nt][r] = sv;
                mx = fmaxf(mx, sv);
            }
        mx = fmaxf(mx, __shfl_xor(mx, 16));
        mx = fmaxf(mx, __shfl_xor(mx, 32));
        const float mn = fmaxf(rm, mx);
        const float al = fexp2(rm - mn);
        float ps = 0.f;
#pragma unroll
        for (int nt = 0; nt < 2; ++nt)
#pragma unroll
            for (int r = 0; r < 4; ++r) {
                float p = fexp2(sc[nt][r] - mn);
                sc[nt][r] = p;
                ps += p;
            }
        ps += __shfl_xor(ps, 16);
        ps += __shfl_xor(ps, 32);
        rl = rl * al + ps;
        rm = mn;

        // P: C-layout -> per-wave LDS -> B-operand layout (packed b32 writes, one b128 read)
        short* pl = Pl[wave];
#pragma unroll
        for (int nt = 0; nt < 2; ++nt)
#pragma unroll
            for (int hh = 0; hh < 2; ++hh)
                *(unsigned*)&pl[l16 * PSTR + nt * 16 + g * 4 + 2 * hh] =
                    pack2(sc[nt][2 * hh], sc[nt][2 * hh + 1]);
        bf16x8 pf = *(const bf16x8*)&pl[l16 * PSTR + g * 8];

        // rescale O^T, then O^T += V^T · P^T
#pragma unroll
        for (int dt = 0; dt < 8; ++dt) {
            o[dt][0] *= al; o[dt][1] *= al; o[dt][2] *= al; o[dt][3] *= al;
        }
#pragma unroll
        for (int dt = 0; dt < 8; ++dt)
            o[dt] = __builtin_amdgcn_mfma_f32_16x16x32_bf16(vf[dt], pf, o[dt], 0, 0, 0);
    }

    // epilogue: lane holds O[q=qrow][d = dt*16 + g*4 + r] -> contiguous float4 stores
    const float inv = 1.0f / rl;
    float* op = outg + (size_t)(b * SEQ + qrow) * QROW + h * HEAD_DIM + g * 4;
#pragma unroll
    for (int dt = 0; dt < 8; ++dt) {
        float4 w = { o[dt][0] * inv, o[dt][1] * inv, o[dt][2] * inv, o[dt][3] * inv };
        *(float4*)(op + dt * 16) = w;
    }
}

extern "C" void kernel_launch(void* const* d_in, const int* in_sizes, int n_in,
                              void* d_out, int out_size, void* d_ws, size_t ws_size,
                              hipStream_t stream) {
    const float* q = (const float*)d_in[0];
    const float* k = (const float*)d_in[1];
    const float* v = (const float*)d_in[2];
    float* out = (float*)d_out;

    // workspace: Kb bf16 [b][hk][s][d] (8.39 MB) + V^T bf16 [b][hk][d][s] (8.39 MB)
    short* kbuf = (short*)d_ws;
    short* vtbuf = kbuf + (size_t)BATCH * NUM_KV_HEADS * SEQ * HEAD_DIM;

    conv_k <<<2048, 256, 0, stream>>>(k, kbuf);
    conv_vt<<<2048, 256, 0, stream>>>(v, vtbuf);

    dim3 grid(SEQ / BQ, NUM_HEADS, BATCH);
    fattn_kernel<<<grid, dim3(256), 0, stream>>>(q, kbuf, vtbuf, out);
}

// Round 3
// 273.450 us; speedup vs baseline: 3.7095x; 3.7095x over previous
//
#include <hip/hip_runtime.h>

#define NUM_HEADS 32
#define HEAD_DIM 128
#define NUM_KV_HEADS 8
#define SEQ 2048
#define BATCH 2
#define BQ 64            // q rows per block (16 per wave, 4 waves)
#define TKV 32           // kv rows per iteration
#define PSTR 40          // P round-trip LDS row stride (shorts)
#define QROW (NUM_HEADS * HEAD_DIM)      // 4096 floats
#define KROW (NUM_KV_HEADS * HEAD_DIM)   // 1024 floats

typedef __attribute__((ext_vector_type(8))) short bf16x8;
typedef __attribute__((ext_vector_type(4))) float f32x4;

__device__ __forceinline__ short f2bf(float f) {
    unsigned u = __float_as_uint(f);
    u += 0x7fffu + ((u >> 16) & 1u);
    return (short)(u >> 16);
}
__device__ __forceinline__ unsigned pack2(float a, float b) {
    return ((unsigned)(unsigned short)f2bf(a)) | (((unsigned)(unsigned short)f2bf(b)) << 16);
}
__device__ __forceinline__ float fexp2(float x) { return __builtin_amdgcn_exp2f(x); }

// ---- pre-pass: K fp32 [b][s][hk][d] -> bf16 fragment-tiled ----
// layout per (b,hk): [kvt(128)][s(4)][lane(64)][8], so a wave fragment load at
// base + lane*8 shorts is one contiguous 1KB transaction.
// chunk content: A-operand m=l16 -> kv=kvt*16+l16, k=g*8+j -> d=s*32+g*8+j.
__global__ __launch_bounds__(256)
void conv_k(const float* __restrict__ kg, short* __restrict__ kb) {
    int gid  = blockIdx.x * 256 + threadIdx.x;   // 524288 chunks
    int lane = gid & 63, g = lane >> 4, l16 = lane & 15;
    int s    = (gid >> 6) & 3;
    int kvt  = (gid >> 8) & 127;
    int hk   = (gid >> 15) & 7;
    int b    = gid >> 18;
    const float* in = kg + ((size_t)(b * SEQ + kvt * 16 + l16) * NUM_KV_HEADS + hk) * HEAD_DIM
                         + s * 32 + g * 8;
    float4 a = *(const float4*)in;
    float4 c = *(const float4*)(in + 4);
    bf16x8 o = { f2bf(a.x), f2bf(a.y), f2bf(a.z), f2bf(a.w),
                 f2bf(c.x), f2bf(c.y), f2bf(c.z), f2bf(c.w) };
    *(bf16x8*)(kb + (size_t)gid * 8) = o;   // gid order == layout order
}

// ---- pre-pass: V fp32 [b][s][hk][d] -> bf16 V^T fragment-tiled ----
// layout per (b,hk): [dt(8)][kvc(64)][lane(64)][8]
// chunk content: A-operand m=l16 -> d=dt*16+l16, k=g*8+j -> kv=kvc*32+g*8+j.
// LDS transpose so global reads stay coalesced.
__global__ __launch_bounds__(256)
void conv_vt(const float* __restrict__ vg, short* __restrict__ vt) {
    int bidx = blockIdx.x;                    // 1024 = (b, hk, kvc)
    int kvc = bidx & 63, hk = (bidx >> 6) & 7, b = bidx >> 9;
    __shared__ float T[32][132];              // +4 pad: transpose reads conflict-light
    int tid = threadIdx.x;
#pragma unroll
    for (int i = 0; i < 4; ++i) {
        int slot = i * 256 + tid, row = slot >> 5, col = (slot & 31) * 4;
        float4 v = *(const float4*)(vg + ((size_t)(b * SEQ + kvc * 32 + row) * NUM_KV_HEADS + hk)
                                          * HEAD_DIM + col);
        *(float4*)&T[row][col] = v;
    }
    __syncthreads();
    short* dst = vt + (size_t)(b * NUM_KV_HEADS + hk) * SEQ * HEAD_DIM;
#pragma unroll
    for (int cc = 0; cc < 2; ++cc) {
        int c = tid * 2 + cc;                 // 512 chunks per tile
        int dt = c >> 6, lane = c & 63, g = lane >> 4, l16 = lane & 15;
        bf16x8 o;
#pragma unroll
        for (int j = 0; j < 8; ++j) o[j] = f2bf(T[g * 8 + j][dt * 16 + l16]);
        *(bf16x8*)(dst + ((size_t)(dt * 64 + kvc) * 64 + lane) * 8) = o;
    }
}

// ---- main: barrier-free flash attention, S^T formulation, coalesced fragments ----
__global__ __launch_bounds__(256, 4)
void fattn_kernel(const float* __restrict__ qg, const short* __restrict__ kb,
                  const short* __restrict__ vt, float* __restrict__ outg) {
    const int tid  = threadIdx.x;
    const int wave = tid >> 6;
    const int lane = tid & 63;
    const int g    = lane >> 4;
    const int l16  = lane & 15;

    // XCD swizzle: bid%8 = hk -> each XCD sees 2 (b,hk) combos (2MB KV, L2-resident).
    // t_rev in the slowest bits -> heavy (high-q) tiles dispatch first.
    const int bid  = (int)blockIdx.x;
    const int hk   = bid & 7;
    const int rest = bid >> 3;
    const int b    = rest & 1;
    const int j    = (rest >> 1) & 3;
    const int qt   = 31 - (rest >> 3);
    const int h    = hk * 4 + j;

    const int q0w  = qt * BQ + wave * 16;
    const int qrow = q0w + l16;

    __shared__ short Pl[4][16 * PSTR];

    // Q fragments (B-operand: n=q=l16, k=g*8+j)
    bf16x8 qf[4];
    {
        const float* qp = qg + (size_t)(b * SEQ + qrow) * QROW + h * HEAD_DIM + g * 8;
#pragma unroll
        for (int s = 0; s < 4; ++s) {
            float4 a = *(const float4*)(qp + s * 32);
            float4 c = *(const float4*)(qp + s * 32 + 4);
            bf16x8 f = { f2bf(a.x), f2bf(a.y), f2bf(a.z), f2bf(a.w),
                         f2bf(c.x), f2bf(c.y), f2bf(c.z), f2bf(c.w) };
            qf[s] = f;
        }
    }

    const short* kbase = kb + (size_t)(b * NUM_KV_HEADS + hk) * SEQ * HEAD_DIM + lane * 8;
    const short* vbase = vt + (size_t)(b * NUM_KV_HEADS + hk) * SEQ * HEAD_DIM + lane * 8;

    f32x4 o[8];
#pragma unroll
    for (int i = 0; i < 8; ++i) o[i] = (f32x4){0.f, 0.f, 0.f, 0.f};
    float rm = -1e30f, rl = 0.f;

    const float sscale = 0.08838834764831845f * 1.4426950408889634f;  // scale*log2(e)
    const int ntk = (q0w + 16 + TKV - 1) / TKV;   // per-wave causal trips

    for (int kt = 0; kt < ntk; ++kt) {
        const int kv0 = kt * TKV;

        // K fragments: one contiguous 1KB wave load each
        bf16x8 kf[2][4];
#pragma unroll
        for (int nt = 0; nt < 2; ++nt)
#pragma unroll
            for (int s = 0; s < 4; ++s)
                kf[nt][s] = *(const bf16x8*)(kbase + ((size_t)((kt * 2 + nt) * 4 + s) << 9));

        // S^T = K·Q^T
        f32x4 sacc[2];
#pragma unroll
        for (int nt = 0; nt < 2; ++nt) {
            f32x4 acc = {0.f, 0.f, 0.f, 0.f};
#pragma unroll
            for (int s = 0; s < 4; ++s)
                acc = __builtin_amdgcn_mfma_f32_16x16x32_bf16(kf[nt][s], qf[s], acc, 0, 0, 0);
            sacc[nt] = acc;
        }

        // V^T fragments issued early (contiguous 1KB wave loads)
        bf16x8 vf[8];
#pragma unroll
        for (int dt = 0; dt < 8; ++dt)
            vf[dt] = *(const bf16x8*)(vbase + ((size_t)(dt * 64 + kt) << 9));

        // masked online softmax; row q=l16 spans the 4 quads
        float sc[2][4];
        float mx = -1e30f;
        const int kvb = kv0 + g * 4;
#pragma unroll
        for (int nt = 0; nt < 2; ++nt)
#pragma unroll
            for (int r = 0; r < 4; ++r) {
                float sv = sacc[nt][r] * sscale;
                sv = (kvb + nt * 16 + r <= qrow) ? sv : -1e30f;
                sc[nt][r] = sv;
                mx = fmaxf(mx, sv);
            }
        mx = fmaxf(mx, __shfl_xor(mx, 16));
        mx = fmaxf(mx, __shfl_xor(mx, 32));
        const float mn = fmaxf(rm, mx);
        const float al = fexp2(rm - mn);
        float ps = 0.f;
#pragma unroll
        for (int nt = 0; nt < 2; ++nt)
#pragma unroll
            for (int r = 0; r < 4; ++r) {
                float p = fexp2(sc[nt][r] - mn);
                sc[nt][r] = p;
                ps += p;
            }
        ps += __shfl_xor(ps, 16);
        ps += __shfl_xor(ps, 32);
        rl = rl * al + ps;
        rm = mn;

        // P: C-layout -> per-wave LDS -> A-operand layout
        short* pl = Pl[wave];
#pragma unroll
        for (int nt = 0; nt < 2; ++nt)
#pragma unroll
            for (int hh = 0; hh < 2; ++hh)
                *(unsigned*)&pl[l16 * PSTR + nt * 16 + g * 4 + 2 * hh] =
                    pack2(sc[nt][2 * hh], sc[nt][2 * hh + 1]);
        bf16x8 pf = *(const bf16x8*)&pl[l16 * PSTR + g * 8];

        // rescale O^T, then O^T += V^T · P^T
#pragma unroll
        for (int dt = 0; dt < 8; ++dt) {
            o[dt][0] *= al; o[dt][1] *= al; o[dt][2] *= al; o[dt][3] *= al;
        }
#pragma unroll
        for (int dt = 0; dt < 8; ++dt)
            o[dt] = __builtin_amdgcn_mfma_f32_16x16x32_bf16(vf[dt], pf, o[dt], 0, 0, 0);
    }

    // epilogue: lane holds O[q=qrow][d = dt*16 + g*4 + r] -> float4 stores
    const float inv = 1.0f / rl;
    float* op = outg + (size_t)(b * SEQ + qrow) * QROW + h * HEAD_DIM + g * 4;
#pragma unroll
    for (int dt = 0; dt < 8; ++dt) {
        float4 w = { o[dt][0] * inv, o[dt][1] * inv, o[dt][2] * inv, o[dt][3] * inv };
        *(float4*)(op + dt * 16) = w;
    }
}

extern "C" void kernel_launch(void* const* d_in, const int* in_sizes, int n_in,
                              void* d_out, int out_size, void* d_ws, size_t ws_size,
                              hipStream_t stream) {
    const float* q = (const float*)d_in[0];
    const float* k = (const float*)d_in[1];
    const float* v = (const float*)d_in[2];
    float* out = (float*)d_out;

    short* kbuf  = (short*)d_ws;                                          // 8.39 MB
    short* vtbuf = kbuf + (size_t)BATCH * NUM_KV_HEADS * SEQ * HEAD_DIM;  // 8.39 MB

    conv_k <<<2048, 256, 0, stream>>>(k, kbuf);
    conv_vt<<<1024, 256, 0, stream>>>(v, vtbuf);

    fattn_kernel<<<dim3(2048), dim3(256), 0, stream>>>(q, kbuf, vtbuf, out);
}